// Round 9
// baseline (176.476 us; speedup 1.0000x reference)
//
#include <hip/hip_runtime.h>
#include <float.h>
#include <math.h>

#define IW 1216
#define IH 352
#define W4 304
#define MIND 0.1f
#define MAXD 100.0f
// tile: 128 wide x 32 tall output; single LDS buffer rows rel -13..44 (ra = rel+13)
// S col c <-> global f4 (xb4 + c - 3) <-> px (4c-12 .. 4c-9) relative to x0
#define RB 58
#define SWD 39

__device__ __forceinline__ float4 vmax4(float4 a, float4 b) {
    return make_float4(fmaxf(a.x,b.x), fmaxf(a.y,b.y), fmaxf(a.z,b.z), fmaxf(a.w,b.w));
}
__device__ __forceinline__ float4 vmin4(float4 a, float4 b) {
    return make_float4(fminf(a.x,b.x), fminf(a.y,b.y), fminf(a.z,b.z), fminf(a.w,b.w));
}

#define CE(a,b) { float _l = fminf(a,b), _h = fmaxf(a,b); a = _l; b = _h; }
#define FE(a,b) { float _h = fmaxf(a,b), _l = fminf(a,b); a = _h; b = _l; }
#define SORT5(a,b,c,d,e) { CE(a,b) CE(d,e) CE(c,e) CE(c,d) CE(a,d) CE(a,c) CE(b,e) CE(b,d) CE(b,c) }
#define MM8(s0,s1,s2,s3,s4,s5,s6,s7) { CE(s0,s1) CE(s2,s3) CE(s4,s5) CE(s6,s7) \
    CE(s0,s2) CE(s0,s4) CE(s0,s6) CE(s1,s7) CE(s3,s7) CE(s5,s7) }
#define MM7(s0,s1,s2,s3,s4,s5,s6) { CE(s0,s1) CE(s2,s3) CE(s4,s5) \
    CE(s0,s2) CE(s0,s4) CE(s0,s6) CE(s1,s6) CE(s3,s6) CE(s5,s6) }

// ---- partial order-statistic networks (0-1 verified; outputs are value-SETS) ----
__device__ __forceinline__ void top2_5(float a, float b, float c, float d, float e,
                                       float& o1, float& o2) {
    float mab = fmaxf(a,b), nab = fminf(a,b);
    float mcd = fmaxf(c,d), ncd = fminf(c,d);
    float hi4 = fmaxf(mab, mcd);
    float lo2 = fmaxf(fminf(mab, mcd), fmaxf(nab, ncd));
    o2 = fmaxf(hi4, e);
    o1 = fmaxf(fminf(hi4, e), lo2);
}
__device__ __forceinline__ void bot2_5(float a, float b, float c, float d, float e,
                                       float& o1, float& o2) {
    float mab = fmaxf(a,b), nab = fminf(a,b);
    float mcd = fmaxf(c,d), ncd = fminf(c,d);
    float lo4 = fminf(nab, ncd);
    float hi2 = fminf(fmaxf(nab, ncd), fminf(mab, mcd));
    o2 = fminf(lo4, e);
    o1 = fminf(fmaxf(lo4, e), hi2);
}
__device__ __forceinline__ void top3_5(float a, float b, float c, float d, float e,
                                       float& o1, float& o2, float& o3) {
    CE(a,b) CE(c,d) CE(a,c) CE(b,d) CE(a,e) CE(b,c) CE(b,e)
    o1 = c; o2 = d; o3 = e;
}
__device__ __forceinline__ void bot3_5(float a, float b, float c, float d, float e,
                                       float& o1, float& o2, float& o3) {
    FE(a,b) FE(c,d) FE(a,c) FE(b,d) FE(a,e) FE(b,c) FE(b,e)
    o1 = c; o2 = d; o3 = e;
}
__device__ __forceinline__ void mid3_5(float a, float b, float c, float d, float e,
                                       float& o1, float& o2, float& o3) {
    CE(a,b) CE(c,d) CE(a,c) CE(b,d) CE(a,e) CE(d,e)
    o1 = b; o2 = c; o3 = d;
}

__global__ __launch_bounds__(256, 4) void mega_k(const float4* __restrict__ in,
                                                 float4* __restrict__ out,
                                                 float w0, float w1, float w2) {
    __shared__ float4 S[RB][SWD];   // 36192 B
    int b  = blockIdx.x;
    int sw = (b & 7) * 220 + (b >> 3);       // 1760 = 8*220 XCD chunk swizzle
    int tx = sw % 10; int t2 = sw / 10;
    int ty = t2 % 11; int n  = t2 / 11;
    int x0 = tx * 128, y0 = ty * 32;
    int tid = threadIdx.x;
    const long ib = (long)n * (IH * W4);
    const int xb4 = x0 >> 2;
    const bool interior = (tx >= 1) && (tx <= 8) && (ty >= 1) && (ty <= 9);

    // ---------------- P01: global load + invert + h-dilate9 -> S rows 0..57, cols 0..37 -----
    for (int it = tid; it < RB * 6; it += 256) {
        int j = it % 6, r = it / 6;
        int c0 = 7 * j;
        int nc = (j == 5) ? 3 : 7;
        int gy = y0 + r - 13;
        bool rok = (unsigned)gy < IH;
        float4 lf[9];
        #pragma unroll
        for (int q = 0; q < 9; ++q) {
            if (q < nc + 2) {
                int g = xb4 + c0 - 4 + q;
                float4 v;
                if (rok && (unsigned)g < W4) {
                    v = in[ib + gy * W4 + g];
                    v.x = v.x > MIND ? MAXD - v.x : v.x;
                    v.y = v.y > MIND ? MAXD - v.y : v.y;
                    v.z = v.z > MIND ? MAXD - v.z : v.z;
                    v.w = v.w > MIND ? MAXD - v.w : v.w;
                } else { v.x = v.y = v.z = v.w = -FLT_MAX; }
                lf[q] = v;
            }
        }
        #pragma unroll
        for (int s = 0; s < 7; ++s) {
            if (s < nc) {
                float t[12];
                *(float4*)&t[0] = lf[s];
                *(float4*)&t[4] = lf[s + 1];
                *(float4*)&t[8] = lf[s + 2];
                float core = fmaxf(fmaxf(fmaxf(t[3],t[4]), fmaxf(t[5],t[6])), fmaxf(t[7],t[8]));
                float a12 = fmaxf(t[1], t[2]), a910 = fmaxf(t[9], t[10]);
                float4 o;
                o.x = fmaxf(fmaxf(core, a12), t[0]);
                o.y = fmaxf(fmaxf(core, a12), t[9]);
                o.z = fmaxf(fmaxf(core, t[2]), a910);
                o.w = fmaxf(fmaxf(core, a910), t[11]);
                S[r][c0 + s] = o;
            }
        }
    }
    __syncthreads();

    // ---------------- P2: v-dilate9 in-place (rows 4..53, cols 0..37), reg-staged -----------
    {
        int c = tid % 38, k = tid / 38;
        int ra0 = 4 + 9 * k;
        int run = min(9, 54 - ra0);      // k=5 -> 5
        float4 o[9];
        if (k < 6) {
            float4 w[9];
            #pragma unroll
            for (int q = 0; q < 8; ++q) w[q] = S[ra0 - 4 + q][c];
            #pragma unroll
            for (int s = 0; s < 9; ++s) {
                if (s < run) {
                    w[8] = S[ra0 + 4 + s][c];
                    float4 m = w[0];
                    #pragma unroll
                    for (int q = 1; q < 9; ++q) m = vmax4(m, w[q]);
                    o[s] = m;
                    #pragma unroll
                    for (int q = 0; q < 8; ++q) w[q] = w[q + 1];
                }
            }
        }
        __syncthreads();
        if (k < 6) {
            #pragma unroll
            for (int s = 0; s < 9; ++s)
                if (s < run) S[ra0 + s][c] = o[s];
        }
        __syncthreads();
    }

    // ---------------- P3: h-erode5 (rows 4..53, write cols 1..36), reg-staged ---------------
    {
        float4 o[8];
        #pragma unroll
        for (int ii = 0; ii < 8; ++ii) {
            int i = tid + 256 * ii;
            if (i < 50 * 36) {
                int ra = i / 36 + 4, cb = i % 36;
                float t[12];
                *(float4*)&t[0] = S[ra][cb];
                *(float4*)&t[4] = S[ra][cb + 1];
                *(float4*)&t[8] = S[ra][cb + 2];
                if (!interior) {
                    bool rOK = (unsigned)(y0 + ra - 13) < IH;
                    #pragma unroll
                    for (int kk = 2; kk <= 9; ++kk) {
                        int gx = x0 + 4 * cb - 12 + kk;
                        t[kk] = (rOK && (unsigned)gx < IW) ? t[kk] : FLT_MAX;
                    }
                }
                float m34 = fminf(t[3], t[4]), m56 = fminf(t[5], t[6]), m78 = fminf(t[7], t[8]);
                float4 oo;
                oo.x = fminf(fminf(t[2], m34), m56);
                oo.y = fminf(fminf(m34, m56), t[7]);
                oo.z = fminf(fminf(t[4], m56), m78);
                oo.w = fminf(fminf(m56, m78), t[9]);
                o[ii] = oo;
            }
        }
        __syncthreads();
        #pragma unroll
        for (int ii = 0; ii < 8; ++ii) {
            int i = tid + 256 * ii;
            if (i < 50 * 36) { int ra = i / 36 + 4, cb = i % 36; S[ra][cb + 1] = o[ii]; }
        }
        __syncthreads();
    }

    // ---------------- P4: v-erode5 in-place (rows 6..51, cols 1..36), reg-staged ------------
    {
        int c = tid % 36, k = tid / 36;
        int ra0 = 6 + 7 * k;
        int run = min(7, 52 - ra0);      // k=6 -> 4
        float4 o[7];
        if (k < 7) {
            float4 w[5];
            #pragma unroll
            for (int q = 0; q < 4; ++q) w[q] = S[ra0 - 2 + q][c + 1];
            #pragma unroll
            for (int s = 0; s < 7; ++s) {
                if (s < run) {
                    w[4] = S[ra0 + 2 + s][c + 1];
                    float4 m = w[0];
                    #pragma unroll
                    for (int q = 1; q < 5; ++q) m = vmin4(m, w[q]);
                    o[s] = m;
                    #pragma unroll
                    for (int q = 0; q < 4; ++q) w[q] = w[q + 1];
                }
            }
        }
        __syncthreads();
        if (k < 7) {
            #pragma unroll
            for (int s = 0; s < 7; ++s)
                if (s < run) S[ra0 + s][c + 1] = o[s];
        }
        __syncthreads();
    }

    // ---------------- P56: h-dilate7 (regs) + v-dilate7 + fill (rows 9..48, cols 2..35) -----
    {
        int c = tid % 34, k = tid / 34;
        int ra0 = 9 + 6 * k;
        int run = min(6, 49 - ra0);      // k=6 -> 4
        float4 o[6];
        if (k < 7) {
            auto hrow = [&](int rr) -> float4 {
                float t[12];
                *(float4*)&t[0] = S[rr][c + 1];
                *(float4*)&t[4] = S[rr][c + 2];
                *(float4*)&t[8] = S[rr][c + 3];
                if (!interior) {
                    bool rOK = (unsigned)(y0 + rr - 13) < IH;
                    #pragma unroll
                    for (int kk = 1; kk <= 10; ++kk) {
                        int gx = x0 + 4 * c - 8 + kk;
                        t[kk] = (rOK && (unsigned)gx < IW) ? t[kk] : -FLT_MAX;
                    }
                }
                float core = fmaxf(fmaxf(t[4], t[5]), fmaxf(t[6], t[7]));
                float a23 = fmaxf(t[2], t[3]), a89 = fmaxf(t[8], t[9]);
                float4 r;
                r.x = fmaxf(fmaxf(core, a23), t[1]);
                r.y = fmaxf(fmaxf(core, a23), t[8]);
                r.z = fmaxf(fmaxf(core, t[3]), a89);
                r.w = fmaxf(fmaxf(core, a89), t[10]);
                return r;
            };
            float4 hw[7];
            #pragma unroll
            for (int q = 0; q < 6; ++q) hw[q] = hrow(ra0 - 3 + q);
            #pragma unroll
            for (int s = 0; s < 6; ++s) {
                if (s < run) {
                    hw[6] = hrow(ra0 + 3 + s);
                    float4 m = hw[0];
                    #pragma unroll
                    for (int q = 1; q < 7; ++q) m = vmax4(m, hw[q]);
                    float4 cl = S[ra0 + s][c + 2];
                    float4 oo;
                    oo.x = cl.x < MIND ? m.x : cl.x;
                    oo.y = cl.y < MIND ? m.y : cl.y;
                    oo.z = cl.z < MIND ? m.z : cl.z;
                    oo.w = cl.w < MIND ? m.w : cl.w;
                    o[s] = oo;
                    #pragma unroll
                    for (int q = 0; q < 6; ++q) hw[q] = hw[q + 1];
                }
            }
        }
        __syncthreads();
        if (k < 7) {
            #pragma unroll
            for (int s = 0; s < 6; ++s)
                if (s < run) S[ra0 + s][c + 2] = o[s];
        }
        __syncthreads();
    }

    // ---------------- P7: 5x5 median (rows 11..46, cols 2..35), reg-staged ------------------
    {
        int c = tid % 34, k = tid / 34;
        int ra0 = 11 + 5 * k;
        int rlen = (k == 6) ? 6 : 5;     // rows 11..40 (5x6) + 41..46 (6)
        float4 o[6];
        if (k < 7) {
            float rows_[5][8];
            auto loadrow = [&](float* rw, int rr) {
                float4 q0 = S[rr][c + 1], q1 = S[rr][c + 2], q2 = S[rr][c + 3];
                float tmp[8] = {q0.z, q0.w, q1.x, q1.y, q1.z, q1.w, q2.x, q2.y};
                if (interior) {
                    #pragma unroll
                    for (int j2 = 0; j2 < 8; ++j2) rw[j2] = tmp[j2];
                } else {
                    bool rOK = (unsigned)(y0 + rr - 13) < IH;
                    #pragma unroll
                    for (int j2 = 0; j2 < 8; ++j2) {
                        int gx = x0 + 4 * c - 6 + j2;
                        rw[j2] = (rOK && (unsigned)gx < IW) ? tmp[j2] : 0.0f;
                    }
                }
            };
            #pragma unroll
            for (int q = 0; q < 4; ++q) loadrow(rows_[q], ra0 - 2 + q);
            #pragma unroll
            for (int st = 0; st < 6; ++st) {
                if (st < rlen) {
                    loadrow(rows_[4], ra0 + 2 + st);
                    float cs[8][5];
                    #pragma unroll
                    for (int j2 = 0; j2 < 8; ++j2) {
                        float a0 = rows_[0][j2], a1 = rows_[1][j2], a2 = rows_[2][j2],
                              a3 = rows_[3][j2], a4 = rows_[4][j2];
                        SORT5(a0, a1, a2, a3, a4)
                        cs[j2][0] = a0; cs[j2][1] = a1; cs[j2][2] = a2; cs[j2][3] = a3; cs[j2][4] = a4;
                    }
                    float rr4[4];
                    #pragma unroll
                    for (int p = 0; p < 4; ++p) {
                        float s0,s1,s2,s3,s4,s5,s6,s7,g0,g1,g2,g3,g4;
                        top2_5(cs[p][0],cs[p+1][0],cs[p+2][0],cs[p+3][0],cs[p+4][0], s0, s1);
                        top3_5(cs[p][1],cs[p+1][1],cs[p+2][1],cs[p+3][1],cs[p+4][1], s2, s3, s4);
                        mid3_5(cs[p][2],cs[p+1][2],cs[p+2][2],cs[p+3][2],cs[p+4][2], s5, s6, s7);
                        bot3_5(cs[p][3],cs[p+1][3],cs[p+2][3],cs[p+3][3],cs[p+4][3], g0, g1, g2);
                        bot2_5(cs[p][4],cs[p+1][4],cs[p+2][4],cs[p+3][4],cs[p+4][4], g3, g4);
                        MM8(s0,s1,s2,s3,s4,s5,s6,s7)
                        s0 = g0; s7 = g1;
                        MM8(s0,s1,s2,s3,s4,s5,s6,s7)
                        s0 = g2; s7 = g3;
                        MM8(s0,s1,s2,s3,s4,s5,s6,s7)
                        s0 = g4;
                        MM7(s0,s1,s2,s3,s4,s5,s6)
                        CE(s1,s2) CE(s3,s4) CE(s1,s3) CE(s2,s4)
                        float mn = fminf(s2, s3), mx = fmaxf(s2, s3);
                        rr4[p] = fmaxf(mn, fminf(mx, s5));
                    }
                    o[st] = make_float4(rr4[0], rr4[1], rr4[2], rr4[3]);
                    #pragma unroll
                    for (int q = 0; q < 4; ++q) {
                        #pragma unroll
                        for (int q2 = 0; q2 < 8; ++q2) rows_[q][q2] = rows_[q + 1][q2];
                    }
                }
            }
        }
        __syncthreads();
        if (k < 7) {
            #pragma unroll
            for (int st = 0; st < 6; ++st)
                if (st < rlen) S[ra0 + st][c + 2] = o[st];
        }
        __syncthreads();
    }

    // ---------------- P89: h-gauss (regs) + v-gauss + select + invert + store ---------------
    {
        int c = tid % 32, k = tid / 32;       // k = 0..7, 4 output rows each
        int ra0 = 13 + 4 * k;
        bool lfix = (tx == 0) && (c == 0);
        bool rfix = (tx == 9) && (c == 15);
        auto hgrow = [&](int rr) -> float4 {
            float4 q0 = S[rr][c + 2], q1 = S[rr][c + 3], q2 = S[rr][c + 4];
            float t[8] = {q0.z, q0.w, q1.x, q1.y, q1.z, q1.w, q2.x, q2.y};
            if (lfix) { t[0] = t[4]; t[1] = t[3]; }
            if (rfix) { t[6] = t[4]; t[7] = t[3]; }
            float4 r;
            r.x = w2 * (t[0] + t[4]) + w1 * (t[1] + t[3]) + w0 * t[2];
            r.y = w2 * (t[1] + t[5]) + w1 * (t[2] + t[4]) + w0 * t[3];
            r.z = w2 * (t[2] + t[6]) + w1 * (t[3] + t[5]) + w0 * t[4];
            r.w = w2 * (t[3] + t[7]) + w1 * (t[4] + t[6]) + w0 * t[5];
            return r;
        };
        float4 hw[8];
        #pragma unroll
        for (int q = 0; q < 8; ++q) hw[q] = hgrow(ra0 - 2 + q);
        bool ybt = (ty == 0) || (ty == 10);
        int gx4 = xb4 + c;
        #pragma unroll
        for (int s = 0; s < 4; ++s) {
            int ra = ra0 + s;
            int gy = y0 + ra - 13;                 // always in [0, IH)
            float4 bl;
            if (!ybt) {
                bl.x = w2 * (hw[s].x + hw[s+4].x) + w1 * (hw[s+1].x + hw[s+3].x) + w0 * hw[s+2].x;
                bl.y = w2 * (hw[s].y + hw[s+4].y) + w1 * (hw[s+1].y + hw[s+3].y) + w0 * hw[s+2].y;
                bl.z = w2 * (hw[s].z + hw[s+4].z) + w1 * (hw[s+1].z + hw[s+3].z) + w0 * hw[s+2].z;
                bl.w = w2 * (hw[s].w + hw[s+4].w) + w1 * (hw[s+1].w + hw[s+3].w) + w0 * hw[s+2].w;
            } else {
                float we0 = w2, we1 = w1, we2 = w0, we3 = w1, we4 = w2;
                if (gy == 0)        { we0 = 0; we1 = 0; we3 = 2*w1; we4 = 2*w2; }
                else if (gy == 1)   { we0 = 0; we2 = w0 + w2; }
                else if (gy == 350) { we2 = w0 + w2; we4 = 0; }
                else if (gy == 351) { we0 = 2*w2; we1 = 2*w1; we3 = 0; we4 = 0; }
                bl.x = we0*hw[s].x + we1*hw[s+1].x + we2*hw[s+2].x + we3*hw[s+3].x + we4*hw[s+4].x;
                bl.y = we0*hw[s].y + we1*hw[s+1].y + we2*hw[s+2].y + we3*hw[s+3].y + we4*hw[s+4].y;
                bl.z = we0*hw[s].z + we1*hw[s+1].z + we2*hw[s+2].z + we3*hw[s+3].z + we4*hw[s+4].z;
                bl.w = we0*hw[s].w + we1*hw[s+1].w + we2*hw[s+2].w + we3*hw[s+3].w + we4*hw[s+4].w;
            }
            float4 dm = S[ra][c + 3];
            float4 oo;
            { float sv = dm.x > MIND ? bl.x : dm.x; oo.x = sv > MIND ? MAXD - sv : sv; }
            { float sv = dm.y > MIND ? bl.y : dm.y; oo.y = sv > MIND ? MAXD - sv : sv; }
            { float sv = dm.z > MIND ? bl.z : dm.z; oo.z = sv > MIND ? MAXD - sv : sv; }
            { float sv = dm.w > MIND ? bl.w : dm.w; oo.w = sv > MIND ? MAXD - sv : sv; }
            if (gx4 < W4) out[ib + (long)gy * W4 + gx4] = oo;
        }
    }
}

extern "C" void kernel_launch(void* const* d_in, const int* in_sizes, int n_in,
                              void* d_out, int out_size, void* d_ws, size_t ws_size,
                              hipStream_t stream) {
    const float4* in = (const float4*)d_in[0];
    float4* O = (float4*)d_out;

    // Gaussian weights: sigma = 1.1 -> 2*sigma^2 = 2.42
    float c2 = 2.42f;
    float e1 = expf(-1.0f / c2);
    float e4 = expf(-4.0f / c2);
    float s  = 1.0f + 2.0f * e1 + 2.0f * e4;
    float w0 = 1.0f / s, w1 = e1 / s, w2 = e4 / s;

    mega_k<<<dim3(1760), dim3(256), 0, stream>>>(in, O, w0, w1, w2);
}

// Round 10
// 166.065 us; speedup vs baseline: 1.0627x; 1.0627x over previous
//
#include <hip/hip_runtime.h>
#include <float.h>
#include <math.h>

#define IW 1216
#define IH 352
#define W4 304
#define MIND 0.1f
#define MAXD 100.0f
// tile: 128 wide x 24 tall output; single LDS buffer rows rel -13..36 (ra = rel+13)
// S col c <-> global f4 (xb4 + c - 3) <-> px (4c-12 .. 4c-9) relative to x0
#define RB 50
#define SWD 39

__device__ __forceinline__ float4 vmax4(float4 a, float4 b) {
    return make_float4(fmaxf(a.x,b.x), fmaxf(a.y,b.y), fmaxf(a.z,b.z), fmaxf(a.w,b.w));
}
__device__ __forceinline__ float4 vmin4(float4 a, float4 b) {
    return make_float4(fminf(a.x,b.x), fminf(a.y,b.y), fminf(a.z,b.z), fminf(a.w,b.w));
}

#define CE(a,b) { float _l = fminf(a,b), _h = fmaxf(a,b); a = _l; b = _h; }
#define FE(a,b) { float _h = fmaxf(a,b), _l = fminf(a,b); a = _h; b = _l; }
#define SORT5(a,b,c,d,e) { CE(a,b) CE(d,e) CE(c,e) CE(c,d) CE(a,d) CE(a,c) CE(b,e) CE(b,d) CE(b,c) }
#define MM8(s0,s1,s2,s3,s4,s5,s6,s7) { CE(s0,s1) CE(s2,s3) CE(s4,s5) CE(s6,s7) \
    CE(s0,s2) CE(s0,s4) CE(s0,s6) CE(s1,s7) CE(s3,s7) CE(s5,s7) }
#define MM7(s0,s1,s2,s3,s4,s5,s6) { CE(s0,s1) CE(s2,s3) CE(s4,s5) \
    CE(s0,s2) CE(s0,s4) CE(s0,s6) CE(s1,s6) CE(s3,s6) CE(s5,s6) }

// ---- partial order-statistic networks (0-1 verified; outputs are value-SETS) ----
__device__ __forceinline__ void top2_5(float a, float b, float c, float d, float e,
                                       float& o1, float& o2) {
    float mab = fmaxf(a,b), nab = fminf(a,b);
    float mcd = fmaxf(c,d), ncd = fminf(c,d);
    float hi4 = fmaxf(mab, mcd);
    float lo2 = fmaxf(fminf(mab, mcd), fmaxf(nab, ncd));
    o2 = fmaxf(hi4, e);
    o1 = fmaxf(fminf(hi4, e), lo2);
}
__device__ __forceinline__ void bot2_5(float a, float b, float c, float d, float e,
                                       float& o1, float& o2) {
    float mab = fmaxf(a,b), nab = fminf(a,b);
    float mcd = fmaxf(c,d), ncd = fminf(c,d);
    float lo4 = fminf(nab, ncd);
    float hi2 = fminf(fmaxf(nab, ncd), fminf(mab, mcd));
    o2 = fminf(lo4, e);
    o1 = fminf(fmaxf(lo4, e), hi2);
}
__device__ __forceinline__ void top3_5(float a, float b, float c, float d, float e,
                                       float& o1, float& o2, float& o3) {
    CE(a,b) CE(c,d) CE(a,c) CE(b,d) CE(a,e) CE(b,c) CE(b,e)
    o1 = c; o2 = d; o3 = e;
}
__device__ __forceinline__ void bot3_5(float a, float b, float c, float d, float e,
                                       float& o1, float& o2, float& o3) {
    FE(a,b) FE(c,d) FE(a,c) FE(b,d) FE(a,e) FE(b,c) FE(b,e)
    o1 = c; o2 = d; o3 = e;
}
__device__ __forceinline__ void mid3_5(float a, float b, float c, float d, float e,
                                       float& o1, float& o2, float& o3) {
    CE(a,b) CE(c,d) CE(a,c) CE(b,d) CE(a,e) CE(d,e)
    o1 = b; o2 = c; o3 = d;
}

__global__ __launch_bounds__(256, 4) void mega_k(const float4* __restrict__ in,
                                                 float4* __restrict__ out,
                                                 float w0, float w1, float w2) {
    __shared__ float4 S[RB][SWD];   // 31200 B -> 5 blocks/CU
    int b  = blockIdx.x;
    int sw = (b & 7) * 300 + (b >> 3);       // 2400 = 8*300 XCD chunk swizzle
    int tx = sw % 10; int t2 = sw / 10;
    int ty = t2 % 15; int n  = t2 / 15;
    int x0 = tx * 128, y0 = ty * 24;
    int tid = threadIdx.x;
    const long ib = (long)n * (IH * W4);
    const int xb4 = x0 >> 2;
    const bool interior = (tx >= 1) && (tx <= 8) && (ty >= 1) && (ty <= 13);

    // ---------------- P01: global load + invert + h-dilate9 -> S rows 0..49, cols 0..37 -----
    for (int it = tid; it < RB * 6; it += 256) {
        int j = it % 6, r = it / 6;
        int c0 = 7 * j;
        int nc = (j == 5) ? 3 : 7;
        int gy = y0 + r - 13;
        bool rok = (unsigned)gy < IH;
        float4 lf[9];
        #pragma unroll
        for (int q = 0; q < 9; ++q) {
            if (q < nc + 2) {
                int g = xb4 + c0 - 4 + q;
                float4 v;
                if (rok && (unsigned)g < W4) {
                    v = in[ib + gy * W4 + g];
                    v.x = v.x > MIND ? MAXD - v.x : v.x;
                    v.y = v.y > MIND ? MAXD - v.y : v.y;
                    v.z = v.z > MIND ? MAXD - v.z : v.z;
                    v.w = v.w > MIND ? MAXD - v.w : v.w;
                } else { v.x = v.y = v.z = v.w = -FLT_MAX; }
                lf[q] = v;
            }
        }
        #pragma unroll
        for (int s = 0; s < 7; ++s) {
            if (s < nc) {
                float t[12];
                *(float4*)&t[0] = lf[s];
                *(float4*)&t[4] = lf[s + 1];
                *(float4*)&t[8] = lf[s + 2];
                float core = fmaxf(fmaxf(fmaxf(t[3],t[4]), fmaxf(t[5],t[6])), fmaxf(t[7],t[8]));
                float a12 = fmaxf(t[1], t[2]), a910 = fmaxf(t[9], t[10]);
                float4 o;
                o.x = fmaxf(fmaxf(core, a12), t[0]);
                o.y = fmaxf(fmaxf(core, a12), t[9]);
                o.z = fmaxf(fmaxf(core, t[2]), a910);
                o.w = fmaxf(fmaxf(core, a910), t[11]);
                S[r][c0 + s] = o;
            }
        }
    }
    __syncthreads();

    // ---------------- P2: v-dilate9 in-place (rows 4..45, cols 0..37), reg-staged -----------
    {
        int c = tid % 38, k = tid / 38;
        int ra0 = 4 + 7 * k;
        int run = min(7, 46 - ra0);      // k=5 -> 7 (39..45)
        float4 o[7];
        if (k < 6) {
            float4 w[9];
            #pragma unroll
            for (int q = 0; q < 8; ++q) w[q] = S[ra0 - 4 + q][c];
            #pragma unroll
            for (int s = 0; s < 7; ++s) {
                if (s < run) {
                    w[8] = S[ra0 + 4 + s][c];
                    float4 m = w[0];
                    #pragma unroll
                    for (int q = 1; q < 9; ++q) m = vmax4(m, w[q]);
                    o[s] = m;
                    #pragma unroll
                    for (int q = 0; q < 8; ++q) w[q] = w[q + 1];
                }
            }
        }
        __syncthreads();
        if (k < 6) {
            #pragma unroll
            for (int s = 0; s < 7; ++s)
                if (s < run) S[ra0 + s][c] = o[s];
        }
        __syncthreads();
    }

    // ---------------- P3: h-erode5 (rows 4..45, write cols 1..36), reg-staged ---------------
    {
        float4 o[6];
        #pragma unroll
        for (int ii = 0; ii < 6; ++ii) {
            int i = tid + 256 * ii;
            if (i < 42 * 36) {
                int ra = i / 36 + 4, cb = i % 36;
                float t[12];
                *(float4*)&t[0] = S[ra][cb];
                *(float4*)&t[4] = S[ra][cb + 1];
                *(float4*)&t[8] = S[ra][cb + 2];
                if (!interior) {
                    bool rOK = (unsigned)(y0 + ra - 13) < IH;
                    #pragma unroll
                    for (int kk = 2; kk <= 9; ++kk) {
                        int gx = x0 + 4 * cb - 12 + kk;
                        t[kk] = (rOK && (unsigned)gx < IW) ? t[kk] : FLT_MAX;
                    }
                }
                float m34 = fminf(t[3], t[4]), m56 = fminf(t[5], t[6]), m78 = fminf(t[7], t[8]);
                float4 oo;
                oo.x = fminf(fminf(t[2], m34), m56);
                oo.y = fminf(fminf(m34, m56), t[7]);
                oo.z = fminf(fminf(t[4], m56), m78);
                oo.w = fminf(fminf(m56, m78), t[9]);
                o[ii] = oo;
            }
        }
        __syncthreads();
        #pragma unroll
        for (int ii = 0; ii < 6; ++ii) {
            int i = tid + 256 * ii;
            if (i < 42 * 36) { int ra = i / 36 + 4, cb = i % 36; S[ra][cb + 1] = o[ii]; }
        }
        __syncthreads();
    }

    // ---------------- P4: v-erode5 in-place (rows 6..43, cols 1..36), reg-staged ------------
    {
        int c = tid % 36, k = tid / 36;
        int ra0 = 6 + 6 * k;
        int run = min(6, 44 - ra0);      // k=6 -> 2
        float4 o[6];
        if (k < 7) {
            float4 w[5];
            #pragma unroll
            for (int q = 0; q < 4; ++q) w[q] = S[ra0 - 2 + q][c + 1];
            #pragma unroll
            for (int s = 0; s < 6; ++s) {
                if (s < run) {
                    w[4] = S[ra0 + 2 + s][c + 1];
                    float4 m = w[0];
                    #pragma unroll
                    for (int q = 1; q < 5; ++q) m = vmin4(m, w[q]);
                    o[s] = m;
                    #pragma unroll
                    for (int q = 0; q < 4; ++q) w[q] = w[q + 1];
                }
            }
        }
        __syncthreads();
        if (k < 7) {
            #pragma unroll
            for (int s = 0; s < 6; ++s)
                if (s < run) S[ra0 + s][c + 1] = o[s];
        }
        __syncthreads();
    }

    // ---------------- P56: h-dilate7 (regs) + v-dilate7 + fill (rows 9..40, cols 2..35) -----
    {
        int c = tid % 34, k = tid / 34;
        int ra0 = 9 + 5 * k;
        int run = min(5, 41 - ra0);      // k=6 -> 2
        float4 o[5];
        if (k < 7) {
            auto hrow = [&](int rr) -> float4 {
                float t[12];
                *(float4*)&t[0] = S[rr][c + 1];
                *(float4*)&t[4] = S[rr][c + 2];
                *(float4*)&t[8] = S[rr][c + 3];
                if (!interior) {
                    bool rOK = (unsigned)(y0 + rr - 13) < IH;
                    #pragma unroll
                    for (int kk = 1; kk <= 10; ++kk) {
                        int gx = x0 + 4 * c - 8 + kk;
                        t[kk] = (rOK && (unsigned)gx < IW) ? t[kk] : -FLT_MAX;
                    }
                }
                float core = fmaxf(fmaxf(t[4], t[5]), fmaxf(t[6], t[7]));
                float a23 = fmaxf(t[2], t[3]), a89 = fmaxf(t[8], t[9]);
                float4 r;
                r.x = fmaxf(fmaxf(core, a23), t[1]);
                r.y = fmaxf(fmaxf(core, a23), t[8]);
                r.z = fmaxf(fmaxf(core, t[3]), a89);
                r.w = fmaxf(fmaxf(core, a89), t[10]);
                return r;
            };
            float4 hw[7];
            #pragma unroll
            for (int q = 0; q < 6; ++q) hw[q] = hrow(ra0 - 3 + q);
            #pragma unroll
            for (int s = 0; s < 5; ++s) {
                if (s < run) {
                    hw[6] = hrow(ra0 + 3 + s);
                    float4 m = hw[0];
                    #pragma unroll
                    for (int q = 1; q < 7; ++q) m = vmax4(m, hw[q]);
                    float4 cl = S[ra0 + s][c + 2];
                    float4 oo;
                    oo.x = cl.x < MIND ? m.x : cl.x;
                    oo.y = cl.y < MIND ? m.y : cl.y;
                    oo.z = cl.z < MIND ? m.z : cl.z;
                    oo.w = cl.w < MIND ? m.w : cl.w;
                    o[s] = oo;
                    #pragma unroll
                    for (int q = 0; q < 6; ++q) hw[q] = hw[q + 1];
                }
            }
        }
        __syncthreads();
        if (k < 7) {
            #pragma unroll
            for (int s = 0; s < 5; ++s)
                if (s < run) S[ra0 + s][c + 2] = o[s];
        }
        __syncthreads();
    }

    // ---------------- P7: 5x5 median (rows 11..38, cols 2..35), reg-staged ------------------
    {
        int c = tid % 34, k = tid / 34;
        int ra0 = 11 + 4 * k;            // 7 groups x 4 rows = 28 exact
        float4 o[4];
        if (k < 7) {
            float rows_[5][8];
            auto loadrow = [&](float* rw, int rr) {
                float4 q0 = S[rr][c + 1], q1 = S[rr][c + 2], q2 = S[rr][c + 3];
                float tmp[8] = {q0.z, q0.w, q1.x, q1.y, q1.z, q1.w, q2.x, q2.y};
                if (interior) {
                    #pragma unroll
                    for (int j2 = 0; j2 < 8; ++j2) rw[j2] = tmp[j2];
                } else {
                    bool rOK = (unsigned)(y0 + rr - 13) < IH;
                    #pragma unroll
                    for (int j2 = 0; j2 < 8; ++j2) {
                        int gx = x0 + 4 * c - 6 + j2;
                        rw[j2] = (rOK && (unsigned)gx < IW) ? tmp[j2] : 0.0f;
                    }
                }
            };
            #pragma unroll
            for (int q = 0; q < 4; ++q) loadrow(rows_[q], ra0 - 2 + q);
            #pragma unroll
            for (int st = 0; st < 4; ++st) {
                loadrow(rows_[4], ra0 + 2 + st);
                float cs[8][5];
                #pragma unroll
                for (int j2 = 0; j2 < 8; ++j2) {
                    float a0 = rows_[0][j2], a1 = rows_[1][j2], a2 = rows_[2][j2],
                          a3 = rows_[3][j2], a4 = rows_[4][j2];
                    SORT5(a0, a1, a2, a3, a4)
                    cs[j2][0] = a0; cs[j2][1] = a1; cs[j2][2] = a2; cs[j2][3] = a3; cs[j2][4] = a4;
                }
                float rr4[4];
                #pragma unroll
                for (int p = 0; p < 4; ++p) {
                    float s0,s1,s2,s3,s4,s5,s6,s7,g0,g1,g2,g3,g4;
                    top2_5(cs[p][0],cs[p+1][0],cs[p+2][0],cs[p+3][0],cs[p+4][0], s0, s1);
                    top3_5(cs[p][1],cs[p+1][1],cs[p+2][1],cs[p+3][1],cs[p+4][1], s2, s3, s4);
                    mid3_5(cs[p][2],cs[p+1][2],cs[p+2][2],cs[p+3][2],cs[p+4][2], s5, s6, s7);
                    bot3_5(cs[p][3],cs[p+1][3],cs[p+2][3],cs[p+3][3],cs[p+4][3], g0, g1, g2);
                    bot2_5(cs[p][4],cs[p+1][4],cs[p+2][4],cs[p+3][4],cs[p+4][4], g3, g4);
                    MM8(s0,s1,s2,s3,s4,s5,s6,s7)
                    s0 = g0; s7 = g1;
                    MM8(s0,s1,s2,s3,s4,s5,s6,s7)
                    s0 = g2; s7 = g3;
                    MM8(s0,s1,s2,s3,s4,s5,s6,s7)
                    s0 = g4;
                    MM7(s0,s1,s2,s3,s4,s5,s6)
                    CE(s1,s2) CE(s3,s4) CE(s1,s3) CE(s2,s4)
                    float mn = fminf(s2, s3), mx = fmaxf(s2, s3);
                    rr4[p] = fmaxf(mn, fminf(mx, s5));
                }
                o[st] = make_float4(rr4[0], rr4[1], rr4[2], rr4[3]);
                #pragma unroll
                for (int q = 0; q < 4; ++q) {
                    #pragma unroll
                    for (int q2 = 0; q2 < 8; ++q2) rows_[q][q2] = rows_[q + 1][q2];
                }
            }
        }
        __syncthreads();
        if (k < 7) {
            #pragma unroll
            for (int st = 0; st < 4; ++st) S[ra0 + st][c + 2] = o[st];
        }
        __syncthreads();
    }

    // ---------------- P89: h-gauss (regs) + v-gauss + select + invert + store ---------------
    {
        int c = tid % 32, k = tid / 32;       // k = 0..7, 3 output rows each
        int ra0 = 13 + 3 * k;
        bool lfix = (tx == 0) && (c == 0);
        bool rfix = (tx == 9) && (c == 15);
        auto hgrow = [&](int rr) -> float4 {
            float4 q0 = S[rr][c + 2], q1 = S[rr][c + 3], q2 = S[rr][c + 4];
            float t[8] = {q0.z, q0.w, q1.x, q1.y, q1.z, q1.w, q2.x, q2.y};
            if (lfix) { t[0] = t[4]; t[1] = t[3]; }
            if (rfix) { t[6] = t[4]; t[7] = t[3]; }
            float4 r;
            r.x = w2 * (t[0] + t[4]) + w1 * (t[1] + t[3]) + w0 * t[2];
            r.y = w2 * (t[1] + t[5]) + w1 * (t[2] + t[4]) + w0 * t[3];
            r.z = w2 * (t[2] + t[6]) + w1 * (t[3] + t[5]) + w0 * t[4];
            r.w = w2 * (t[3] + t[7]) + w1 * (t[4] + t[6]) + w0 * t[5];
            return r;
        };
        float4 hw[7];
        #pragma unroll
        for (int q = 0; q < 7; ++q) hw[q] = hgrow(ra0 - 2 + q);
        bool ybt = (ty == 0) || (ty == 14);
        int gx4 = xb4 + c;
        #pragma unroll
        for (int s = 0; s < 3; ++s) {
            int ra = ra0 + s;
            int gy = y0 + ra - 13;
            float4 bl;
            if (!ybt) {
                bl.x = w2 * (hw[s].x + hw[s+4].x) + w1 * (hw[s+1].x + hw[s+3].x) + w0 * hw[s+2].x;
                bl.y = w2 * (hw[s].y + hw[s+4].y) + w1 * (hw[s+1].y + hw[s+3].y) + w0 * hw[s+2].y;
                bl.z = w2 * (hw[s].z + hw[s+4].z) + w1 * (hw[s+1].z + hw[s+3].z) + w0 * hw[s+2].z;
                bl.w = w2 * (hw[s].w + hw[s+4].w) + w1 * (hw[s+1].w + hw[s+3].w) + w0 * hw[s+2].w;
            } else {
                float we0 = w2, we1 = w1, we2 = w0, we3 = w1, we4 = w2;
                if (gy == 0)        { we0 = 0; we1 = 0; we3 = 2*w1; we4 = 2*w2; }
                else if (gy == 1)   { we0 = 0; we2 = w0 + w2; }
                else if (gy == 350) { we2 = w0 + w2; we4 = 0; }
                else if (gy == 351) { we0 = 2*w2; we1 = 2*w1; we3 = 0; we4 = 0; }
                bl.x = we0*hw[s].x + we1*hw[s+1].x + we2*hw[s+2].x + we3*hw[s+3].x + we4*hw[s+4].x;
                bl.y = we0*hw[s].y + we1*hw[s+1].y + we2*hw[s+2].y + we3*hw[s+3].y + we4*hw[s+4].y;
                bl.z = we0*hw[s].z + we1*hw[s+1].z + we2*hw[s+2].z + we3*hw[s+3].z + we4*hw[s+4].z;
                bl.w = we0*hw[s].w + we1*hw[s+1].w + we2*hw[s+2].w + we3*hw[s+3].w + we4*hw[s+4].w;
            }
            float4 dm = S[ra][c + 3];
            float4 oo;
            { float sv = dm.x > MIND ? bl.x : dm.x; oo.x = sv > MIND ? MAXD - sv : sv; }
            { float sv = dm.y > MIND ? bl.y : dm.y; oo.y = sv > MIND ? MAXD - sv : sv; }
            { float sv = dm.z > MIND ? bl.z : dm.z; oo.z = sv > MIND ? MAXD - sv : sv; }
            { float sv = dm.w > MIND ? bl.w : dm.w; oo.w = sv > MIND ? MAXD - sv : sv; }
            if (gy < IH && gx4 < W4) out[ib + (long)gy * W4 + gx4] = oo;
        }
    }
}

extern "C" void kernel_launch(void* const* d_in, const int* in_sizes, int n_in,
                              void* d_out, int out_size, void* d_ws, size_t ws_size,
                              hipStream_t stream) {
    const float4* in = (const float4*)d_in[0];
    float4* O = (float4*)d_out;

    // Gaussian weights: sigma = 1.1 -> 2*sigma^2 = 2.42
    float c2 = 2.42f;
    float e1 = expf(-1.0f / c2);
    float e4 = expf(-4.0f / c2);
    float s  = 1.0f + 2.0f * e1 + 2.0f * e4;
    float w0 = 1.0f / s, w1 = e1 / s, w2 = e4 / s;

    mega_k<<<dim3(2400), dim3(256), 0, stream>>>(in, O, w0, w1, w2);
}